// Round 5
// baseline (459.185 us; speedup 1.0000x reference)
//
#include <hip/hip_runtime.h>
#include <hip/hip_bf16.h>

using bf16 = __hip_bfloat16;
typedef __attribute__((ext_vector_type(4))) float f32x4;
typedef __attribute__((ext_vector_type(8))) short bf16x8;

__device__ __forceinline__ unsigned short bfbits(float f) {
    bf16 h = __float2bfloat16(f);
    return __builtin_bit_cast(unsigned short, h);
}

__device__ __forceinline__ void g2l16(const void* g, void* l) {
    __builtin_amdgcn_global_load_lds(
        (const __attribute__((address_space(1))) unsigned int*)g,
        (__attribute__((address_space(3))) unsigned int*)l, 16, 0, 0);
}

// ---------------- cast f32 -> bf16 (vectorized) ----------------
__global__ void castk(const float* __restrict__ in, bf16* __restrict__ out, int n4) {
    int stride = gridDim.x * blockDim.x;
    for (int i = blockIdx.x * blockDim.x + threadIdx.x; i < n4; i += stride) {
        float4 v = reinterpret_cast<const float4*>(in)[i];
        ushort4 o;
        o.x = bfbits(v.x); o.y = bfbits(v.y); o.z = bfbits(v.z); o.w = bfbits(v.w);
        reinterpret_cast<ushort4*>(out)[i] = o;
    }
}

// ================= 256x256-tile 8-wave GEMM, double-buffered, 2 blocks/CU ==========
// C = A @ B^T. A:[M,ldk] bf16 rm; Bm:[N,ldk] bf16 rm. BK=32, 2-buffer LDS (64KB)
// so 2 blocks co-reside per CU (TLP hides the per-tile drain, m114/m97 mechanism).
// Per K-tile: 12 ds_read upfront (partial lgkm waits), 4 stage-issues for kt+1,
// 32 MFMA under setprio, vmcnt(0)+barrier (drain hidden by sibling block).
// EPI 0: QKV scatter (+per-tensor bias) -> [B,H,S,DK] bf16
// EPI 1: relu(acc+bias) -> bf16 [M,N]
// EPI 2: raw f32 acc -> outp + slice*M*N  (split-K partials)
template<int EPI, int SPLITK>
__global__ __launch_bounds__(512, 2)
void gemm256(const bf16* __restrict__ A, const bf16* __restrict__ Bm,
             int N, int ldk, int kloop,
             const float* __restrict__ bias0, const float* __restrict__ bias1,
             const float* __restrict__ bias2,
             void* __restrict__ outp,
             bf16* __restrict__ q_o, bf16* __restrict__ k_o, bf16* __restrict__ v_o) {
    __shared__ __align__(16) char lds[65536];
    const int tid = threadIdx.x;
    const int lane = tid & 63, wave = tid >> 6;
    const int rlo = lane & 15, g = lane >> 4;
    const int wr = wave >> 2, wc = wave & 3;
    const int nbn = N >> 8;
    const int nwg = gridDim.x;
    int wg = (int)blockIdx.x;
    wg = (wg & 7) * (nwg >> 3) + (wg >> 3);   // XCD swizzle (nwg % 8 == 0)
    int slice = 0;
    if constexpr (SPLITK) {
        int half = nwg >> 1;
        slice = (wg >= half) ? 1 : 0;
        wg -= slice * half;
    }
    const int bm = wg / nbn, bn = wg % nbn;
    const size_t ldb = (size_t)ldk * 2;
    const char* abase = (const char*)A + ((size_t)bm << 8) * ldb + (size_t)slice * kloop * 2;
    const char* bbase = (const char*)Bm + ((size_t)bn << 8) * ldb + (size_t)slice * kloop * 2;

    // staging: thread t owns LDS bytes [t*16, t*16+16) of each 8 KB half-tile.
    const int P = tid * 16;
    const int R = P >> 7;
    const int qs = (P & 127) ^ ((R & 7) << 4);          // unswizzle
    const size_t goff0 = (size_t)(R * 2 + (qs >> 6)) * ldb + (qs & 63);
    const size_t ghalf = (size_t)128 * ldb;

    // ds_read lane-constant inner offset (paired-row + 3-bit XOR swizzle)
    const int o_in = (((rlo & 1) << 6) | (g << 4)) ^ (((rlo >> 1) & 7) << 4);
    const int aoff = wr * 8192 + (rlo >> 1) * 128 + o_in;
    const int boff = 16384 + (wc >> 1) * 8192 + (wc & 1) * 4096 + (rlo >> 1) * 128 + o_in;

    const f32x4 fz = {0.f, 0.f, 0.f, 0.f};
    f32x4 acc[8][4];
#pragma unroll
    for (int i = 0; i < 8; ++i)
#pragma unroll
        for (int j = 0; j < 4; ++j) acc[i][j] = fz;

    auto stA = [&](int buf, int h, int kt) {
        g2l16(abase + goff0 + (size_t)h * ghalf + (size_t)kt * 64,
              lds + buf * 32768 + h * 8192 + P);
    };
    auto stB = [&](int buf, int h, int kt) {
        g2l16(bbase + goff0 + (size_t)h * ghalf + (size_t)kt * 64,
              lds + buf * 32768 + 16384 + h * 8192 + P);
    };

    // prologue: stage tile 0 into buf0
    stA(0, 0, 0); stA(0, 1, 0); stB(0, 0, 0); stB(0, 1, 0);
    asm volatile("s_waitcnt vmcnt(0)" ::: "memory");
    __builtin_amdgcn_s_barrier();
    __builtin_amdgcn_sched_barrier(0);

    const int NT = kloop >> 5;
    for (int kt = 0; kt < NT; ++kt) {
        const char* lb = lds + (kt & 1) * 32768;
        const int nbuf = (kt & 1) ^ 1;
        const bool pre = (kt + 1) < NT;

        bf16x8 bfr[4], afr[8];
#pragma unroll
        for (int nf = 0; nf < 4; ++nf)
            bfr[nf] = *reinterpret_cast<const bf16x8*>(lb + nf * 1024 + boff);
#pragma unroll
        for (int i = 0; i < 8; ++i)
            afr[i] = *reinterpret_cast<const bf16x8*>(lb + i * 1024 + aoff);
        if (pre) { stA(nbuf, 0, kt + 1); stA(nbuf, 1, kt + 1);
                   stB(nbuf, 0, kt + 1); stB(nbuf, 1, kt + 1); }
        __builtin_amdgcn_s_setprio(1);
#pragma unroll
        for (int i = 0; i < 4; ++i)
#pragma unroll
            for (int nf = 0; nf < 4; ++nf)
                acc[i][nf] = __builtin_amdgcn_mfma_f32_16x16x32_bf16(afr[i], bfr[nf], acc[i][nf], 0, 0, 0);
#pragma unroll
        for (int i = 0; i < 4; ++i)
#pragma unroll
            for (int nf = 0; nf < 4; ++nf)
                acc[4 + i][nf] = __builtin_amdgcn_mfma_f32_16x16x32_bf16(afr[4 + i], bfr[nf], acc[4 + i][nf], 0, 0, 0);
        __builtin_amdgcn_s_setprio(0);

        if (pre) {
            asm volatile("s_waitcnt vmcnt(0)" ::: "memory");   // tile kt+1 landed
            __builtin_amdgcn_s_barrier();
            __builtin_amdgcn_sched_barrier(0);
        }
    }

    const int gm0 = (bm << 8) + wr * 128;
    const int gn0 = (bn << 8) + wc * 64;
#pragma unroll
    for (int mf = 0; mf < 8; ++mf) {
#pragma unroll
        for (int nf = 0; nf < 4; ++nf) {
            const int gnc = gn0 + nf * 16 + rlo;
#pragma unroll
            for (int r = 0; r < 4; ++r) {
                const int gmr = gm0 + mf * 16 + g * 4 + r;
                float val = acc[mf][nf][r];
                if constexpr (EPI == 0) {
                    int t = gnc >> 10;
                    const float* bp = (t == 0) ? bias0 : ((t == 1) ? bias1 : bias2);
                    val += bp[gnc & 1023];
                    bf16* dst = (t == 0) ? q_o : ((t == 1) ? k_o : v_o);
                    int hh = (gnc >> 7) & 7, d = gnc & 127;
                    int bb = gmr >> 7, s = gmr & 127;
                    dst[(((size_t)bb * 8 + hh) * 128 + s) * 128 + d] = __float2bfloat16(val);
                } else if constexpr (EPI == 1) {
                    val = fmaxf(val + bias0[gnc], 0.f);
                    ((bf16*)outp)[(size_t)gmr * N + gnc] = __float2bfloat16(val);
                } else {
                    float* pp = (float*)outp + (size_t)slice * 8388608;
                    pp[(size_t)gmr * N + gnc] = val;
                }
            }
        }
    }
}

// ---------------- GEMM: C = A @ B^T, 128^2 tile (kept for Wo, N=1024) ----------------
// EPI 2: acc + bias + resid(f32) -> f32 [M,N]
template<int EPI>
__global__ __launch_bounds__(256, 2)
void gemm_bt(const bf16* __restrict__ A, const bf16* __restrict__ Bm,
             int M, int N, int K,
             const float* __restrict__ bias0, const float* __restrict__ resid,
             void* __restrict__ outp) {
    (void)M;
    __shared__ __align__(16) char As[8192];
    __shared__ __align__(16) char Bs[8192];
    int tid = threadIdx.x, wave = tid >> 6, lane = tid & 63;
    int nbn = N >> 7;
    int bm = blockIdx.x / nbn, bn = blockIdx.x % nbn;
    int wm = (wave >> 1) << 6, wn = (wave & 1) << 6;
    int rlo = lane & 15, g = lane >> 4;

    const char* abase = (const char*)(A + (size_t)(bm << 7) * K);
    const char* bbase = (const char*)(Bm + (size_t)(bn << 7) * K);

    const f32x4 fzero = {0.f, 0.f, 0.f, 0.f};
    f32x4 acc[4][4];
#pragma unroll
    for (int i = 0; i < 4; ++i)
#pragma unroll
        for (int j = 0; j < 4; ++j) acc[i][j] = fzero;

    int L0 = wave * 2048 + lane * 16;
    size_t ldbyte = (size_t)K * 2;

    for (int k0 = 0; k0 < K; k0 += 32) {
#pragma unroll
        for (int j = 0; j < 2; ++j) {
            int L = L0 + j * 1024;
            int row = L >> 6;
            int cb = (L & 63) ^ (((row >> 1) & 3) << 4);
            g2l16(abase + (size_t)row * ldbyte + (size_t)k0 * 2 + cb, As + wave * 2048 + j * 1024);
            g2l16(bbase + (size_t)row * ldbyte + (size_t)k0 * 2 + cb, Bs + wave * 2048 + j * 1024);
        }
        __syncthreads();
        bf16x8 af[4], bf8[4];
#pragma unroll
        for (int i = 0; i < 4; ++i) {
            int ra = wm + i * 16 + rlo;
            af[i] = *reinterpret_cast<const bf16x8*>(As + ra * 64 + ((g * 16) ^ (((ra >> 1) & 3) << 4)));
            int rb = wn + i * 16 + rlo;
            bf8[i] = *reinterpret_cast<const bf16x8*>(Bs + rb * 64 + ((g * 16) ^ (((rb >> 1) & 3) << 4)));
        }
#pragma unroll
        for (int mi = 0; mi < 4; ++mi)
#pragma unroll
            for (int ni = 0; ni < 4; ++ni)
                acc[mi][ni] = __builtin_amdgcn_mfma_f32_16x16x32_bf16(af[mi], bf8[ni], acc[mi][ni], 0, 0, 0);
        __syncthreads();
    }

    int gm0 = (bm << 7) + wm, gn0 = (bn << 7) + wn;
#pragma unroll
    for (int mi = 0; mi < 4; ++mi) {
#pragma unroll
        for (int ni = 0; ni < 4; ++ni) {
            int gnc = gn0 + ni * 16 + rlo;
#pragma unroll
            for (int r = 0; r < 4; ++r) {
                int gmr = gm0 + mi * 16 + g * 4 + r;
                float val = acc[mi][ni][r];
                val += bias0[gnc] + resid[(size_t)gmr * N + gnc];
                ((float*)outp)[(size_t)gmr * N + gnc] = val;
            }
        }
    }
}

// ---------------- V transpose per (b,h): V[s][d] -> VT[d][s] ----------------
__global__ __launch_bounds__(256)
void transpose_v(const bf16* __restrict__ V, bf16* __restrict__ VT) {
    __shared__ unsigned short t[128 * 132];
    int bh = blockIdx.x, tid = threadIdx.x;
    const unsigned short* src = (const unsigned short*)(V + (size_t)bh * 16384);
#pragma unroll
    for (int i = 0; i < 8; ++i) {
        int idx = tid + i * 256;
        int srow = idx >> 4;
        int c8 = (idx & 15) * 8;
        ushort4 a = reinterpret_cast<const ushort4*>(src + srow * 128 + c8)[0];
        ushort4 b = reinterpret_cast<const ushort4*>(src + srow * 128 + c8 + 4)[0];
        reinterpret_cast<ushort4*>(t + srow * 132 + c8)[0] = a;
        reinterpret_cast<ushort4*>(t + srow * 132 + c8 + 4)[0] = b;
    }
    __syncthreads();
    unsigned short* dst = (unsigned short*)(VT + (size_t)bh * 16384);
#pragma unroll
    for (int i = 0; i < 8; ++i) {
        int idx = tid + i * 256;
        int drow = idx >> 4;
        int s8 = (idx & 15) * 8;
        ushort4 a, b;
        a.x = t[(s8 + 0) * 132 + drow]; a.y = t[(s8 + 1) * 132 + drow];
        a.z = t[(s8 + 2) * 132 + drow]; a.w = t[(s8 + 3) * 132 + drow];
        b.x = t[(s8 + 4) * 132 + drow]; b.y = t[(s8 + 5) * 132 + drow];
        b.z = t[(s8 + 6) * 132 + drow]; b.w = t[(s8 + 7) * 132 + drow];
        reinterpret_cast<ushort4*>(dst + drow * 128 + s8)[0] = a;
        reinterpret_cast<ushort4*>(dst + drow * 128 + s8 + 4)[0] = b;
    }
}

// ---------------- attention part 1: P = softmax(Q K^T / sqrt(128)) ----------------
__global__ __launch_bounds__(256, 2)
void attn_scores(const bf16* __restrict__ Q, const bf16* __restrict__ K, bf16* __restrict__ P) {
    __shared__ __align__(16) char Qs[32768];
    __shared__ __align__(16) char Ks[32768];
    int bh = blockIdx.x;
    int tid = threadIdx.x, wave = tid >> 6, lane = tid & 63;
    const char* qsrc = (const char*)(Q + (size_t)bh * 16384);
    const char* ksrc = (const char*)(K + (size_t)bh * 16384);
#pragma unroll
    for (int j = 0; j < 8; ++j) {
        int L = wave * 8192 + j * 1024 + lane * 16;
        int row = L >> 8;
        int cb = (L & 255) ^ ((row & 7) << 4);
        g2l16(qsrc + row * 256 + cb, Qs + wave * 8192 + j * 1024);
        g2l16(ksrc + row * 256 + cb, Ks + wave * 8192 + j * 1024);
    }
    __syncthreads();
    int rlo = lane & 15, g = lane >> 4;
    const f32x4 fzero = {0.f, 0.f, 0.f, 0.f};
    f32x4 acc[2][8];
#pragma unroll
    for (int mi = 0; mi < 2; ++mi)
#pragma unroll
        for (int ni = 0; ni < 8; ++ni) acc[mi][ni] = fzero;
#pragma unroll
    for (int kk = 0; kk < 4; ++kk) {
        bf16x8 aq[2], bk8[8];
#pragma unroll
        for (int mi = 0; mi < 2; ++mi) {
            int row = wave * 32 + mi * 16 + rlo;
            aq[mi] = *reinterpret_cast<const bf16x8*>(Qs + row * 256 + ((kk * 64 + g * 16) ^ ((row & 7) << 4)));
        }
#pragma unroll
        for (int ni = 0; ni < 8; ++ni) {
            int row = ni * 16 + rlo;
            bk8[ni] = *reinterpret_cast<const bf16x8*>(Ks + row * 256 + ((kk * 64 + g * 16) ^ ((row & 7) << 4)));
        }
#pragma unroll
        for (int mi = 0; mi < 2; ++mi)
#pragma unroll
            for (int ni = 0; ni < 8; ++ni)
                acc[mi][ni] = __builtin_amdgcn_mfma_f32_16x16x32_bf16(aq[mi], bk8[ni], acc[mi][ni], 0, 0, 0);
    }
    const float scale = 0.088388347648318447f;  // 1/sqrt(128)
    unsigned short* pdst = (unsigned short*)(P + (size_t)bh * 16384);
#pragma unroll
    for (int mi = 0; mi < 2; ++mi) {
#pragma unroll
        for (int r = 0; r < 4; ++r) {
            float m = -3e38f;
#pragma unroll
            for (int ni = 0; ni < 8; ++ni) m = fmaxf(m, acc[mi][ni][r]);
#pragma unroll
            for (int o = 1; o < 16; o <<= 1) m = fmaxf(m, __shfl_xor(m, o));
            m *= scale;
            float e[8];
            float sum = 0.f;
#pragma unroll
            for (int ni = 0; ni < 8; ++ni) { e[ni] = __expf(acc[mi][ni][r] * scale - m); sum += e[ni]; }
#pragma unroll
            for (int o = 1; o < 16; o <<= 1) sum += __shfl_xor(sum, o);
            float inv = 1.f / sum;
            int qrow = wave * 32 + mi * 16 + g * 4 + r;
#pragma unroll
            for (int ni = 0; ni < 8; ++ni)
                pdst[qrow * 128 + ni * 16 + rlo] = bfbits(e[ni] * inv);
        }
    }
}

// ---------------- attention part 2: CTX = (P @ V) @ V ----------------
__global__ __launch_bounds__(256, 2)
void attn_ctx(const bf16* __restrict__ P, const bf16* __restrict__ VT, bf16* __restrict__ CTX) {
    __shared__ __align__(16) char Vs[32768];
    __shared__ __align__(16) char Ts[32768];
    int bh = blockIdx.x, b = bh >> 3, h = bh & 7;
    int tid = threadIdx.x, wave = tid >> 6, lane = tid & 63;
    const char* vsrc = (const char*)(VT + (size_t)bh * 16384);
#pragma unroll
    for (int j = 0; j < 8; ++j) {
        int L = wave * 8192 + j * 1024 + lane * 16;
        int row = L >> 8;
        int cb = (L & 255) ^ ((row & 7) << 4);
        g2l16(vsrc + row * 256 + cb, Vs + wave * 8192 + j * 1024);
    }
    __syncthreads();
    int rlo = lane & 15, g = lane >> 4;
    const char* psrc = (const char*)(P + (size_t)bh * 16384);
    const f32x4 fzero = {0.f, 0.f, 0.f, 0.f};
    f32x4 accT[2][8];
#pragma unroll
    for (int mi = 0; mi < 2; ++mi)
#pragma unroll
        for (int ni = 0; ni < 8; ++ni) accT[mi][ni] = fzero;
#pragma unroll
    for (int kk = 0; kk < 4; ++kk) {
        bf16x8 ap[2], bv8[8];
#pragma unroll
        for (int mi = 0; mi < 2; ++mi) {
            int row = wave * 32 + mi * 16 + rlo;
            ap[mi] = *reinterpret_cast<const bf16x8*>(psrc + (size_t)row * 256 + kk * 64 + g * 16);
        }
#pragma unroll
        for (int ni = 0; ni < 8; ++ni) {
            int row = ni * 16 + rlo;
            bv8[ni] = *reinterpret_cast<const bf16x8*>(Vs + row * 256 + ((kk * 64 + g * 16) ^ ((row & 7) << 4)));
        }
#pragma unroll
        for (int mi = 0; mi < 2; ++mi)
#pragma unroll
            for (int ni = 0; ni < 8; ++ni)
                accT[mi][ni] = __builtin_amdgcn_mfma_f32_16x16x32_bf16(ap[mi], bv8[ni], accT[mi][ni], 0, 0, 0);
    }
#pragma unroll
    for (int mi = 0; mi < 2; ++mi)
#pragma unroll
        for (int ni = 0; ni < 8; ++ni)
#pragma unroll
            for (int r = 0; r < 4; ++r) {
                int trow = wave * 32 + mi * 16 + g * 4 + r;
                int cbyte = ((ni * 16 + rlo) * 2) ^ ((trow & 7) << 4);
                *(unsigned short*)(Ts + trow * 256 + cbyte) = bfbits(accT[mi][ni][r]);
            }
    __syncthreads();
    f32x4 accC[2][8];
#pragma unroll
    for (int mi = 0; mi < 2; ++mi)
#pragma unroll
        for (int ni = 0; ni < 8; ++ni) accC[mi][ni] = fzero;
#pragma unroll
    for (int kk = 0; kk < 4; ++kk) {
        bf16x8 at[2], bv8[8];
#pragma unroll
        for (int mi = 0; mi < 2; ++mi) {
            int row = wave * 32 + mi * 16 + rlo;
            at[mi] = *reinterpret_cast<const bf16x8*>(Ts + row * 256 + ((kk * 64 + g * 16) ^ ((row & 7) << 4)));
        }
#pragma unroll
        for (int ni = 0; ni < 8; ++ni) {
            int row = ni * 16 + rlo;
            bv8[ni] = *reinterpret_cast<const bf16x8*>(Vs + row * 256 + ((kk * 64 + g * 16) ^ ((row & 7) << 4)));
        }
#pragma unroll
        for (int mi = 0; mi < 2; ++mi)
#pragma unroll
            for (int ni = 0; ni < 8; ++ni)
                accC[mi][ni] = __builtin_amdgcn_mfma_f32_16x16x32_bf16(at[mi], bv8[ni], accC[mi][ni], 0, 0, 0);
    }
    unsigned short* cdst = (unsigned short*)CTX;
#pragma unroll
    for (int mi = 0; mi < 2; ++mi)
#pragma unroll
        for (int ni = 0; ni < 8; ++ni)
#pragma unroll
            for (int r = 0; r < 4; ++r) {
                int q = wave * 32 + mi * 16 + g * 4 + r;
                int gm = b * 128 + q;
                int col = h * 128 + ni * 16 + rlo;
                cdst[(size_t)gm * 1024 + col] = bfbits(accC[mi][ni][r]);
            }
}

// ---------------- layernorm over rows of 1024 f32 ----------------
// MODE 0: also write bf16 (Hb)
template<int MODE>
__global__ __launch_bounds__(256)
void ln_k(const float* __restrict__ Y, const float* __restrict__ w, const float* __restrict__ b,
          float* __restrict__ Hf, bf16* __restrict__ Hb) {
    int row = blockIdx.x, tid = threadIdx.x;
    float4 v = reinterpret_cast<const float4*>(Y + (size_t)row * 1024)[tid];
    float s = v.x + v.y + v.z + v.w;
    float q = v.x * v.x + v.y * v.y + v.z * v.z + v.w * v.w;
#pragma unroll
    for (int o = 1; o < 64; o <<= 1) { s += __shfl_xor(s, o); q += __shfl_xor(q, o); }
    __shared__ float ss[4], sq[4];
    if ((tid & 63) == 0) { ss[tid >> 6] = s; sq[tid >> 6] = q; }
    __syncthreads();
    s = ss[0] + ss[1] + ss[2] + ss[3];
    q = sq[0] + sq[1] + sq[2] + sq[3];
    float u = s * (1.f / 1024.f);
    float var = fmaxf(q * (1.f / 1024.f) - u * u, 0.f);
    float rstd = rsqrtf(var + 1e-12f);
    float4 wv = reinterpret_cast<const float4*>(w)[tid];
    float4 bv = reinterpret_cast<const float4*>(b)[tid];
    float o0 = wv.x * (v.x - u) * rstd + bv.x;
    float o1 = wv.y * (v.y - u) * rstd + bv.y;
    float o2 = wv.z * (v.z - u) * rstd + bv.z;
    float o3 = wv.w * (v.w - u) * rstd + bv.w;
    reinterpret_cast<float4*>(Hf + (size_t)row * 1024)[tid] = make_float4(o0, o1, o2, o3);
    if constexpr (MODE == 0) {
        ushort4 ob;
        ob.x = bfbits(o0); ob.y = bfbits(o1); ob.z = bfbits(o2); ob.w = bfbits(o3);
        reinterpret_cast<ushort4*>(Hb)[row * 256 + tid] = ob;
    }
}

// ---- final LN: y = LN(PA + PB + b3 + resid), write f32 out ----
__global__ __launch_bounds__(256)
void ln2k(const float* __restrict__ PA, const float* __restrict__ PB,
          const float* __restrict__ b3, const float* __restrict__ resid,
          const float* __restrict__ w, const float* __restrict__ b,
          float* __restrict__ out) {
    int row = blockIdx.x, tid = threadIdx.x;
    size_t off = (size_t)row * 256 + tid;
    float4 pa = reinterpret_cast<const float4*>(PA)[off];
    float4 pb = reinterpret_cast<const float4*>(PB)[off];
    float4 bi = reinterpret_cast<const float4*>(b3)[tid];
    float4 rs = reinterpret_cast<const float4*>(resid)[off];
    float4 v = make_float4(pa.x + pb.x + bi.x + rs.x, pa.y + pb.y + bi.y + rs.y,
                           pa.z + pb.z + bi.z + rs.z, pa.w + pb.w + bi.w + rs.w);
    float s = v.x + v.y + v.z + v.w;
    float q = v.x * v.x + v.y * v.y + v.z * v.z + v.w * v.w;
#pragma unroll
    for (int o = 1; o < 64; o <<= 1) { s += __shfl_xor(s, o); q += __shfl_xor(q, o); }
    __shared__ float ss[4], sq[4];
    if ((tid & 63) == 0) { ss[tid >> 6] = s; sq[tid >> 6] = q; }
    __syncthreads();
    s = ss[0] + ss[1] + ss[2] + ss[3];
    q = sq[0] + sq[1] + sq[2] + sq[3];
    float u = s * (1.f / 1024.f);
    float var = fmaxf(q * (1.f / 1024.f) - u * u, 0.f);
    float rstd = rsqrtf(var + 1e-12f);
    float4 wv = reinterpret_cast<const float4*>(w)[tid];
    float4 bv = reinterpret_cast<const float4*>(b)[tid];
    float4 o4;
    o4.x = wv.x * (v.x - u) * rstd + bv.x;
    o4.y = wv.y * (v.y - u) * rstd + bv.y;
    o4.z = wv.z * (v.z - u) * rstd + bv.z;
    o4.w = wv.w * (v.w - u) * rstd + bv.w;
    reinterpret_cast<float4*>(out)[off] = o4;
}

extern "C" void kernel_launch(void* const* d_in, const int* in_sizes, int n_in,
                              void* d_out, int out_size, void* d_ws, size_t ws_size,
                              hipStream_t stream) {
    (void)in_sizes; (void)n_in; (void)out_size; (void)ws_size;
    const float* x    = (const float*)d_in[0];
    const float* Wq   = (const float*)d_in[2];
    const float* bq   = (const float*)d_in[3];
    const float* Wk   = (const float*)d_in[4];
    const float* bk   = (const float*)d_in[5];
    const float* Wv   = (const float*)d_in[6];
    const float* bv   = (const float*)d_in[7];
    const float* Wo   = (const float*)d_in[8];
    const float* bo   = (const float*)d_in[9];
    const float* ln1w = (const float*)d_in[10];
    const float* ln1b = (const float*)d_in[11];
    const float* W1   = (const float*)d_in[12];
    const float* b1   = (const float*)d_in[13];
    const float* W2   = (const float*)d_in[14];
    const float* b2   = (const float*)d_in[15];
    const float* W3   = (const float*)d_in[16];
    const float* b3   = (const float*)d_in[17];
    const float* ln2w = (const float*)d_in[18];
    const float* ln2b = (const float*)d_in[19];

    char* ws = (char*)d_ws;
    bf16*  XB    = (bf16*)(ws + 0);
    bf16*  WQKVB = (bf16*)(ws + 16777216);
    bf16*  WOB   = (bf16*)(ws + 23068672);
    bf16*  W1B   = (bf16*)(ws + 25165824);
    bf16*  W2B   = (bf16*)(ws + 29360128);
    bf16*  W3B   = (bf16*)(ws + 46137344);
    bf16*  Qb    = (bf16*)(ws + 54525952);
    bf16*  Kb    = (bf16*)(ws + 71303168);
    bf16*  Vb    = (bf16*)(ws + 88080384);
    bf16*  VTb   = (bf16*)(ws + 104857600);
    bf16*  Pb    = (bf16*)(ws + 121634816);
    bf16*  CTX   = (bf16*)(ws + 138412032);
    float* Y2    = (float*)(ws + 155189248);
    float* H32   = (float*)(ws + 188743680);
    bf16*  HB    = (bf16*)(ws + 222298112);
    bf16*  F1    = (bf16*)(ws + 155189248);   // overlays Y2 (dead after LN1)
    bf16*  F2    = (bf16*)(ws + 54525952);    // overlays Qb..VTb (dead)
    float* PW3   = (float*)(ws + 121634816);  // 67 MB span; clobbers Pb/CTX/Y2 (all dead by W3)

    auto cast = [&](const float* s, bf16* dd, int n4) {
        int nb = (n4 + 255) / 256; if (nb > 2048) nb = 2048;
        castk<<<nb, 256, 0, stream>>>(s, dd, n4);
    };
    cast(x,  XB,             2097152);
    cast(Wq, WQKVB,           262144);
    cast(Wk, WQKVB + 1048576, 262144);
    cast(Wv, WQKVB + 2097152, 262144);
    cast(Wo, WOB,             262144);
    cast(W1, W1B,             524288);
    cast(W2, W2B,            2097152);
    cast(W3, W3B,            1048576);

    // QKV: [8192,1024] @ [3072,1024]^T -> Q,K,V [B,H,S,DK]
    gemm256<0, 0><<<384, 512, 0, stream>>>(XB, WQKVB, 3072, 1024, 1024,
                                           bq, bk, bv, nullptr, Qb, Kb, Vb);
    transpose_v<<<512, 256, 0, stream>>>(Vb, VTb);
    attn_scores<<<512, 256, 0, stream>>>(Qb, Kb, Pb);
    attn_ctx<<<512, 256, 0, stream>>>(Pb, VTb, CTX);
    // attn_out + x -> Y2 (f32)
    gemm_bt<2><<<512, 256, 0, stream>>>(CTX, WOB, 8192, 1024, 1024, bo, x, (void*)Y2);
    ln_k<0><<<8192, 256, 0, stream>>>(Y2, ln1w, ln1b, H32, HB);
    // MLP
    gemm256<1, 0><<<256, 512, 0, stream>>>(HB, W1B, 2048, 1024, 1024,
                                           b1, nullptr, nullptr, (void*)F1, nullptr, nullptr, nullptr);
    gemm256<1, 0><<<512, 512, 0, stream>>>(F1, W2B, 4096, 2048, 2048,
                                           b2, nullptr, nullptr, (void*)F2, nullptr, nullptr, nullptr);
    // W3 split-K=2 -> f32 partials; reduce+bias+resid+LN fused in ln2k
    gemm256<2, 1><<<256, 512, 0, stream>>>(F2, W3B, 1024, 4096, 2048,
                                           nullptr, nullptr, nullptr, (void*)PW3, nullptr, nullptr, nullptr);
    ln2k<<<8192, 256, 0, stream>>>(PW3, PW3 + 8388608, b3, H32, ln2w, ln2b, (float*)d_out);
}

// Round 6
// 434.189 us; speedup vs baseline: 1.0576x; 1.0576x over previous
//
#include <hip/hip_runtime.h>
#include <hip/hip_bf16.h>

using bf16 = __hip_bfloat16;
typedef __attribute__((ext_vector_type(4))) float f32x4;
typedef __attribute__((ext_vector_type(8))) short bf16x8;

__device__ __forceinline__ unsigned short bfbits(float f) {
    bf16 h = __float2bfloat16(f);
    return __builtin_bit_cast(unsigned short, h);
}

__device__ __forceinline__ void g2l16(const void* g, void* l) {
    __builtin_amdgcn_global_load_lds(
        (const __attribute__((address_space(1))) unsigned int*)g,
        (__attribute__((address_space(3))) unsigned int*)l, 16, 0, 0);
}

// ---------------- cast f32 -> bf16 (vectorized) ----------------
__global__ void castk(const float* __restrict__ in, bf16* __restrict__ out, int n4) {
    int stride = gridDim.x * blockDim.x;
    for (int i = blockIdx.x * blockDim.x + threadIdx.x; i < n4; i += stride) {
        float4 v = reinterpret_cast<const float4*>(in)[i];
        ushort4 o;
        o.x = bfbits(v.x); o.y = bfbits(v.y); o.z = bfbits(v.z); o.w = bfbits(v.w);
        reinterpret_cast<ushort4*>(out)[i] = o;
    }
}

// ============ 256x256-tile 8-wave GEMM, BK=64, 4-phase m201-style schedule ============
// C = A @ B^T. A:[M,ldk] bf16 rm; Bm:[N,ldk] bf16 rm. LDS 128KB = 2 buf x (A 32KB + B 32KB).
// Per K-tile: 4 phases, each {ds_read frag subtile | stage 1 half-tile | bar | lgkm0 |
// setprio(1) 16 MFMA setprio(0) | bar}. Counted vmcnt(4) once per tile (T4).
// Stage schedule (hazard-derived): P0/P1 stage B(t+1) halves -> other buf (B reads of
// t-1 done by t-1.P2); P2/P3 stage A(t+2) halves -> current buf (A LDS reads done by P1,
// since quadrant order is a0b0,a1b0,a1b1,a0b1). Every half lands >=3 phases before use;
// vmcnt(4) at P3 certifies through B-h1(t+1). Swizzle: col ^ ((row&7)<<4), 128B rows.
// EPI 0: QKV scatter (+per-tensor bias) -> [B,H,S,DK] bf16
// EPI 1: relu(acc+bias) -> bf16 [M,N]
// EPI 2: raw f32 acc -> outp + slice*M*N  (split-K partials)
template<int EPI, int SPLITK>
__global__ __launch_bounds__(512, 2)
void gemm256(const bf16* __restrict__ A, const bf16* __restrict__ Bm,
             int N, int ldk, int kloop,
             const float* __restrict__ bias0, const float* __restrict__ bias1,
             const float* __restrict__ bias2,
             void* __restrict__ outp,
             bf16* __restrict__ q_o, bf16* __restrict__ k_o, bf16* __restrict__ v_o) {
    __shared__ __align__(16) char lds[131072];
    const int tid = threadIdx.x;
    const int lane = tid & 63, wave = tid >> 6;
    const int rlo = lane & 15, g = lane >> 4;
    const int wr = wave >> 2, wc = wave & 3;
    const int nbn = N >> 8;
    const int nwg = gridDim.x;
    int wg = (int)blockIdx.x;
    wg = (wg & 7) * (nwg >> 3) + (wg >> 3);   // XCD swizzle (nwg % 8 == 0)
    int slice = 0;
    if constexpr (SPLITK) {
        int half = nwg >> 1;
        slice = (wg >= half) ? 1 : 0;
        wg -= slice * half;
    }
    const int bm = wg / nbn, bn = wg % nbn;
    const size_t ldb = (size_t)ldk * 2;
    const char* abase = (const char*)A + ((size_t)bm << 8) * ldb + (size_t)slice * kloop * 2;
    const char* bbase = (const char*)Bm + ((size_t)bn << 8) * ldb + (size_t)slice * kloop * 2;

    // stage one 16KB half-tile (128 rows x 128B), linear LDS dest, pre-unswizzled source
    auto stage = [&](int bufbyte, int region, int h, const char* gbase, int kt) {
#pragma unroll
        for (int j = 0; j < 2; ++j) {
            int P = tid * 16 + j * 8192;
            int row = P >> 7;
            int col = (P & 127) ^ ((row & 7) << 4);
            g2l16(gbase + (size_t)(h * 128 + row) * ldb + (size_t)kt * 128 + col,
                  lds + bufbyte + region * 32768 + h * 16384 + P);
        }
    };

    const int sw = (rlo & 7) << 4;
    const int c0 = (g * 16) ^ sw;          // ks=0 byte col (swizzled)
    const int c1 = (64 | (g * 16)) ^ sw;   // ks=1

    // A quad q (mf = q*4 .. q*4+3), 8 x ds_read_b128
    auto ldA = [&](const char* lb, int q, bf16x8* ar) {
#pragma unroll
        for (int i = 0; i < 4; ++i) {
            const char* rp = lb + wr * 16384 + ((q * 4 + i) * 16 + rlo) * 128;
            ar[i * 2 + 0] = *reinterpret_cast<const bf16x8*>(rp + c0);
            ar[i * 2 + 1] = *reinterpret_cast<const bf16x8*>(rp + c1);
        }
    };
    // B pair p (nf = p*2 .. p*2+1), 4 x ds_read_b128
    auto ldB = [&](const char* lb, int p, bf16x8* br) {
#pragma unroll
        for (int j = 0; j < 2; ++j) {
            const char* rp = lb + 32768 + (wc >> 1) * 16384 +
                             ((wc & 1) * 64 + (p * 2 + j) * 16 + rlo) * 128;
            br[j * 2 + 0] = *reinterpret_cast<const bf16x8*>(rp + c0);
            br[j * 2 + 1] = *reinterpret_cast<const bf16x8*>(rp + c1);
        }
    };

    const f32x4 fz = {0.f, 0.f, 0.f, 0.f};
    f32x4 acc[8][4];
#pragma unroll
    for (int i = 0; i < 8; ++i)
#pragma unroll
        for (int j = 0; j < 4; ++j) acc[i][j] = fz;

    const int NT = kloop >> 6;

    // prologue: tile0 (A+B) -> buf0; A halves of tile1 -> buf1
    stage(0, 0, 0, abase, 0); stage(0, 0, 1, abase, 0);
    stage(0, 1, 0, bbase, 0); stage(0, 1, 1, bbase, 0);
    stage(65536, 0, 0, abase, 1); stage(65536, 0, 1, abase, 1);
    asm volatile("s_waitcnt vmcnt(4)" ::: "memory");
    __builtin_amdgcn_s_barrier();
    __builtin_amdgcn_sched_barrier(0);

    for (int t = 0; t < NT; ++t) {
        const int cbb = (t & 1) * 65536;
        const int obb = cbb ^ 65536;
        const char* lb = lds + cbb;
        bf16x8 a0[8], a1[8], b[4];

        // ---- P0: LD Aq0 + Bp0 | stage B-h0(t+1) | MFMA a0 x b(p0) -> acc[0..3][0..1]
        ldA(lb, 0, a0); ldB(lb, 0, b);
        if (t + 1 < NT) stage(obb, 1, 0, bbase, t + 1);
        __builtin_amdgcn_s_barrier();
        asm volatile("s_waitcnt lgkmcnt(0)" ::: "memory");
        __builtin_amdgcn_sched_barrier(0);
        __builtin_amdgcn_s_setprio(1);
#pragma unroll
        for (int i = 0; i < 4; ++i)
#pragma unroll
            for (int j = 0; j < 2; ++j)
#pragma unroll
                for (int ks = 0; ks < 2; ++ks)
                    acc[i][j] = __builtin_amdgcn_mfma_f32_16x16x32_bf16(a0[i*2+ks], b[j*2+ks], acc[i][j], 0, 0, 0);
        __builtin_amdgcn_s_setprio(0);
        __builtin_amdgcn_s_barrier();

        // ---- P1: LD Aq1 | stage B-h1(t+1) | MFMA a1 x b(p0) -> acc[4..7][0..1]
        ldA(lb, 1, a1);
        if (t + 1 < NT) stage(obb, 1, 1, bbase, t + 1);
        __builtin_amdgcn_s_barrier();
        asm volatile("s_waitcnt lgkmcnt(0)" ::: "memory");
        __builtin_amdgcn_sched_barrier(0);
        __builtin_amdgcn_s_setprio(1);
#pragma unroll
        for (int i = 0; i < 4; ++i)
#pragma unroll
            for (int j = 0; j < 2; ++j)
#pragma unroll
                for (int ks = 0; ks < 2; ++ks)
                    acc[4+i][j] = __builtin_amdgcn_mfma_f32_16x16x32_bf16(a1[i*2+ks], b[j*2+ks], acc[4+i][j], 0, 0, 0);
        __builtin_amdgcn_s_setprio(0);
        __builtin_amdgcn_s_barrier();

        // ---- P2: LD Bp1 | stage A-h0(t+2) | MFMA a1 x b(p1) -> acc[4..7][2..3]
        ldB(lb, 1, b);
        if (t + 2 < NT) stage(cbb, 0, 0, abase, t + 2);
        __builtin_amdgcn_s_barrier();
        asm volatile("s_waitcnt lgkmcnt(0)" ::: "memory");
        __builtin_amdgcn_sched_barrier(0);
        __builtin_amdgcn_s_setprio(1);
#pragma unroll
        for (int i = 0; i < 4; ++i)
#pragma unroll
            for (int j = 0; j < 2; ++j)
#pragma unroll
                for (int ks = 0; ks < 2; ++ks)
                    acc[4+i][2+j] = __builtin_amdgcn_mfma_f32_16x16x32_bf16(a1[i*2+ks], b[j*2+ks], acc[4+i][2+j], 0, 0, 0);
        __builtin_amdgcn_s_setprio(0);
        __builtin_amdgcn_s_barrier();

        // ---- P3: stage A-h1(t+2) | vmcnt | MFMA a0 x b(p1) -> acc[0..3][2..3]
        if (t + 2 < NT) stage(cbb, 0, 1, abase, t + 2);
        if (t + 1 < NT) {
            if (t + 2 < NT) { asm volatile("s_waitcnt vmcnt(4)" ::: "memory"); }
            else            { asm volatile("s_waitcnt vmcnt(0)" ::: "memory"); }
        }
        __builtin_amdgcn_s_barrier();
        __builtin_amdgcn_sched_barrier(0);
        __builtin_amdgcn_s_setprio(1);
#pragma unroll
        for (int i = 0; i < 4; ++i)
#pragma unroll
            for (int j = 0; j < 2; ++j)
#pragma unroll
                for (int ks = 0; ks < 2; ++ks)
                    acc[i][2+j] = __builtin_amdgcn_mfma_f32_16x16x32_bf16(a0[i*2+ks], b[j*2+ks], acc[i][2+j], 0, 0, 0);
        __builtin_amdgcn_s_setprio(0);
        if (t + 1 < NT) {
            __builtin_amdgcn_s_barrier();
            __builtin_amdgcn_sched_barrier(0);
        }
    }

    const int gm0 = (bm << 8) + wr * 128;
    const int gn0 = (bn << 8) + wc * 64;
#pragma unroll
    for (int mf = 0; mf < 8; ++mf) {
#pragma unroll
        for (int nf = 0; nf < 4; ++nf) {
            const int gnc = gn0 + nf * 16 + rlo;
#pragma unroll
            for (int r = 0; r < 4; ++r) {
                const int gmr = gm0 + mf * 16 + g * 4 + r;
                float val = acc[mf][nf][r];
                if constexpr (EPI == 0) {
                    int t = gnc >> 10;
                    const float* bp = (t == 0) ? bias0 : ((t == 1) ? bias1 : bias2);
                    val += bp[gnc & 1023];
                    bf16* dst = (t == 0) ? q_o : ((t == 1) ? k_o : v_o);
                    int hh = (gnc >> 7) & 7, d = gnc & 127;
                    int bb = gmr >> 7, s = gmr & 127;
                    dst[(((size_t)bb * 8 + hh) * 128 + s) * 128 + d] = __float2bfloat16(val);
                } else if constexpr (EPI == 1) {
                    val = fmaxf(val + bias0[gnc], 0.f);
                    ((bf16*)outp)[(size_t)gmr * N + gnc] = __float2bfloat16(val);
                } else {
                    float* pp = (float*)outp + (size_t)slice * 8388608;
                    pp[(size_t)gmr * N + gnc] = val;
                }
            }
        }
    }
}

// ---------------- GEMM: C = A @ B^T, 128^2 tile (kept for Wo, N=1024) ----------------
// EPI 2: acc + bias + resid(f32) -> f32 [M,N]
template<int EPI>
__global__ __launch_bounds__(256, 2)
void gemm_bt(const bf16* __restrict__ A, const bf16* __restrict__ Bm,
             int M, int N, int K,
             const float* __restrict__ bias0, const float* __restrict__ resid,
             void* __restrict__ outp) {
    (void)M;
    __shared__ __align__(16) char As[8192];
    __shared__ __align__(16) char Bs[8192];
    int tid = threadIdx.x, wave = tid >> 6, lane = tid & 63;
    int nbn = N >> 7;
    int bm = blockIdx.x / nbn, bn = blockIdx.x % nbn;
    int wm = (wave >> 1) << 6, wn = (wave & 1) << 6;
    int rlo = lane & 15, g = lane >> 4;

    const char* abase = (const char*)(A + (size_t)(bm << 7) * K);
    const char* bbase = (const char*)(Bm + (size_t)(bn << 7) * K);

    const f32x4 fzero = {0.f, 0.f, 0.f, 0.f};
    f32x4 acc[4][4];
#pragma unroll
    for (int i = 0; i < 4; ++i)
#pragma unroll
        for (int j = 0; j < 4; ++j) acc[i][j] = fzero;

    int L0 = wave * 2048 + lane * 16;
    size_t ldbyte = (size_t)K * 2;

    for (int k0 = 0; k0 < K; k0 += 32) {
#pragma unroll
        for (int j = 0; j < 2; ++j) {
            int L = L0 + j * 1024;
            int row = L >> 6;
            int cb = (L & 63) ^ (((row >> 1) & 3) << 4);
            g2l16(abase + (size_t)row * ldbyte + (size_t)k0 * 2 + cb, As + wave * 2048 + j * 1024);
            g2l16(bbase + (size_t)row * ldbyte + (size_t)k0 * 2 + cb, Bs + wave * 2048 + j * 1024);
        }
        __syncthreads();
        bf16x8 af[4], bf8[4];
#pragma unroll
        for (int i = 0; i < 4; ++i) {
            int ra = wm + i * 16 + rlo;
            af[i] = *reinterpret_cast<const bf16x8*>(As + ra * 64 + ((g * 16) ^ (((ra >> 1) & 3) << 4)));
            int rb = wn + i * 16 + rlo;
            bf8[i] = *reinterpret_cast<const bf16x8*>(Bs + rb * 64 + ((g * 16) ^ (((rb >> 1) & 3) << 4)));
        }
#pragma unroll
        for (int mi = 0; mi < 4; ++mi)
#pragma unroll
            for (int ni = 0; ni < 4; ++ni)
                acc[mi][ni] = __builtin_amdgcn_mfma_f32_16x16x32_bf16(af[mi], bf8[ni], acc[mi][ni], 0, 0, 0);
        __syncthreads();
    }

    int gm0 = (bm << 7) + wm, gn0 = (bn << 7) + wn;
#pragma unroll
    for (int mi = 0; mi < 4; ++mi) {
#pragma unroll
        for (int ni = 0; ni < 4; ++ni) {
            int gnc = gn0 + ni * 16 + rlo;
#pragma unroll
            for (int r = 0; r < 4; ++r) {
                int gmr = gm0 + mi * 16 + g * 4 + r;
                float val = acc[mi][ni][r];
                val += bias0[gnc] + resid[(size_t)gmr * N + gnc];
                ((float*)outp)[(size_t)gmr * N + gnc] = val;
            }
        }
    }
}

// ---------------- V transpose per (b,h): V[s][d] -> VT[d][s] ----------------
__global__ __launch_bounds__(256)
void transpose_v(const bf16* __restrict__ V, bf16* __restrict__ VT) {
    __shared__ unsigned short t[128 * 132];
    int bh = blockIdx.x, tid = threadIdx.x;
    const unsigned short* src = (const unsigned short*)(V + (size_t)bh * 16384);
#pragma unroll
    for (int i = 0; i < 8; ++i) {
        int idx = tid + i * 256;
        int srow = idx >> 4;
        int c8 = (idx & 15) * 8;
        ushort4 a = reinterpret_cast<const ushort4*>(src + srow * 128 + c8)[0];
        ushort4 b = reinterpret_cast<const ushort4*>(src + srow * 128 + c8 + 4)[0];
        reinterpret_cast<ushort4*>(t + srow * 132 + c8)[0] = a;
        reinterpret_cast<ushort4*>(t + srow * 132 + c8 + 4)[0] = b;
    }
    __syncthreads();
    unsigned short* dst = (unsigned short*)(VT + (size_t)bh * 16384);
#pragma unroll
    for (int i = 0; i < 8; ++i) {
        int idx = tid + i * 256;
        int drow = idx >> 4;
        int s8 = (idx & 15) * 8;
        ushort4 a, b;
        a.x = t[(s8 + 0) * 132 + drow]; a.y = t[(s8 + 1) * 132 + drow];
        a.z = t[(s8 + 2) * 132 + drow]; a.w = t[(s8 + 3) * 132 + drow];
        b.x = t[(s8 + 4) * 132 + drow]; b.y = t[(s8 + 5) * 132 + drow];
        b.z = t[(s8 + 6) * 132 + drow]; b.w = t[(s8 + 7) * 132 + drow];
        reinterpret_cast<ushort4*>(dst + drow * 128 + s8)[0] = a;
        reinterpret_cast<ushort4*>(dst + drow * 128 + s8 + 4)[0] = b;
    }
}

// ---------------- attention part 1: P = softmax(Q K^T / sqrt(128)) ----------------
__global__ __launch_bounds__(256, 2)
void attn_scores(const bf16* __restrict__ Q, const bf16* __restrict__ K, bf16* __restrict__ P) {
    __shared__ __align__(16) char Qs[32768];
    __shared__ __align__(16) char Ks[32768];
    int bh = blockIdx.x;
    int tid = threadIdx.x, wave = tid >> 6, lane = tid & 63;
    const char* qsrc = (const char*)(Q + (size_t)bh * 16384);
    const char* ksrc = (const char*)(K + (size_t)bh * 16384);
#pragma unroll
    for (int j = 0; j < 8; ++j) {
        int L = wave * 8192 + j * 1024 + lane * 16;
        int row = L >> 8;
        int cb = (L & 255) ^ ((row & 7) << 4);
        g2l16(qsrc + row * 256 + cb, Qs + wave * 8192 + j * 1024);
        g2l16(ksrc + row * 256 + cb, Ks + wave * 8192 + j * 1024);
    }
    __syncthreads();
    int rlo = lane & 15, g = lane >> 4;
    const f32x4 fzero = {0.f, 0.f, 0.f, 0.f};
    f32x4 acc[2][8];
#pragma unroll
    for (int mi = 0; mi < 2; ++mi)
#pragma unroll
        for (int ni = 0; ni < 8; ++ni) acc[mi][ni] = fzero;
#pragma unroll
    for (int kk = 0; kk < 4; ++kk) {
        bf16x8 aq[2], bk8[8];
#pragma unroll
        for (int mi = 0; mi < 2; ++mi) {
            int row = wave * 32 + mi * 16 + rlo;
            aq[mi] = *reinterpret_cast<const bf16x8*>(Qs + row * 256 + ((kk * 64 + g * 16) ^ ((row & 7) << 4)));
        }
#pragma unroll
        for (int ni = 0; ni < 8; ++ni) {
            int row = ni * 16 + rlo;
            bk8[ni] = *reinterpret_cast<const bf16x8*>(Ks + row * 256 + ((kk * 64 + g * 16) ^ ((row & 7) << 4)));
        }
#pragma unroll
        for (int mi = 0; mi < 2; ++mi)
#pragma unroll
            for (int ni = 0; ni < 8; ++ni)
                acc[mi][ni] = __builtin_amdgcn_mfma_f32_16x16x32_bf16(aq[mi], bk8[ni], acc[mi][ni], 0, 0, 0);
    }
    const float scale = 0.088388347648318447f;  // 1/sqrt(128)
    unsigned short* pdst = (unsigned short*)(P + (size_t)bh * 16384);
#pragma unroll
    for (int mi = 0; mi < 2; ++mi) {
#pragma unroll
        for (int r = 0; r < 4; ++r) {
            float m = -3e38f;
#pragma unroll
            for (int ni = 0; ni < 8; ++ni) m = fmaxf(m, acc[mi][ni][r]);
#pragma unroll
            for (int o = 1; o < 16; o <<= 1) m = fmaxf(m, __shfl_xor(m, o));
            m *= scale;
            float e[8];
            float sum = 0.f;
#pragma unroll
            for (int ni = 0; ni < 8; ++ni) { e[ni] = __expf(acc[mi][ni][r] * scale - m); sum += e[ni]; }
#pragma unroll
            for (int o = 1; o < 16; o <<= 1) sum += __shfl_xor(sum, o);
            float inv = 1.f / sum;
            int qrow = wave * 32 + mi * 16 + g * 4 + r;
#pragma unroll
            for (int ni = 0; ni < 8; ++ni)
                pdst[qrow * 128 + ni * 16 + rlo] = bfbits(e[ni] * inv);
        }
    }
}

// ---------------- attention part 2: CTX = (P @ V) @ V ----------------
__global__ __launch_bounds__(256, 2)
void attn_ctx(const bf16* __restrict__ P, const bf16* __restrict__ VT, bf16* __restrict__ CTX) {
    __shared__ __align__(16) char Vs[32768];
    __shared__ __align__(16) char Ts[32768];
    int bh = blockIdx.x, b = bh >> 3, h = bh & 7;
    int tid = threadIdx.x, wave = tid >> 6, lane = tid & 63;
    const char* vsrc = (const char*)(VT + (size_t)bh * 16384);
#pragma unroll
    for (int j = 0; j < 8; ++j) {
        int L = wave * 8192 + j * 1024 + lane * 16;
        int row = L >> 8;
        int cb = (L & 255) ^ ((row & 7) << 4);
        g2l16(vsrc + row * 256 + cb, Vs + wave * 8192 + j * 1024);
    }
    __syncthreads();
    int rlo = lane & 15, g = lane >> 4;
    const char* psrc = (const char*)(P + (size_t)bh * 16384);
    const f32x4 fzero = {0.f, 0.f, 0.f, 0.f};
    f32x4 accT[2][8];
#pragma unroll
    for (int mi = 0; mi < 2; ++mi)
#pragma unroll
        for (int ni = 0; ni < 8; ++ni) accT[mi][ni] = fzero;
#pragma unroll
    for (int kk = 0; kk < 4; ++kk) {
        bf16x8 ap[2], bv8[8];
#pragma unroll
        for (int mi = 0; mi < 2; ++mi) {
            int row = wave * 32 + mi * 16 + rlo;
            ap[mi] = *reinterpret_cast<const bf16x8*>(psrc + (size_t)row * 256 + kk * 64 + g * 16);
        }
#pragma unroll
        for (int ni = 0; ni < 8; ++ni) {
            int row = ni * 16 + rlo;
            bv8[ni] = *reinterpret_cast<const bf16x8*>(Vs + row * 256 + ((kk * 64 + g * 16) ^ ((row & 7) << 4)));
        }
#pragma unroll
        for (int mi = 0; mi < 2; ++mi)
#pragma unroll
            for (int ni = 0; ni < 8; ++ni)
                accT[mi][ni] = __builtin_amdgcn_mfma_f32_16x16x32_bf16(ap[mi], bv8[ni], accT[mi][ni], 0, 0, 0);
    }
#pragma unroll
    for (int mi = 0; mi < 2; ++mi)
#pragma unroll
        for (int ni = 0; ni < 8; ++ni)
#pragma unroll
            for (int r = 0; r < 4; ++r) {
                int trow = wave * 32 + mi * 16 + g * 4 + r;
                int cbyte = ((ni * 16 + rlo) * 2) ^ ((trow & 7) << 4);
                *(unsigned short*)(Ts + trow * 256 + cbyte) = bfbits(accT[mi][ni][r]);
            }
    __syncthreads();
    f32x4 accC[2][8];
#pragma unroll
    for (int mi = 0; mi < 2; ++mi)
#pragma unroll
        for (int ni = 0; ni < 8; ++ni) accC[mi][ni] = fzero;
#pragma unroll
    for (int kk = 0; kk < 4; ++kk) {
        bf16x8 at[2], bv8[8];
#pragma unroll
        for (int mi = 0; mi < 2; ++mi) {
            int row = wave * 32 + mi * 16 + rlo;
            at[mi] = *reinterpret_cast<const bf16x8*>(Ts + row * 256 + ((kk * 64 + g * 16) ^ ((row & 7) << 4)));
        }
#pragma unroll
        for (int ni = 0; ni < 8; ++ni) {
            int row = ni * 16 + rlo;
            bv8[ni] = *reinterpret_cast<const bf16x8*>(Vs + row * 256 + ((kk * 64 + g * 16) ^ ((row & 7) << 4)));
        }
#pragma unroll
        for (int mi = 0; mi < 2; ++mi)
#pragma unroll
            for (int ni = 0; ni < 8; ++ni)
                accC[mi][ni] = __builtin_amdgcn_mfma_f32_16x16x32_bf16(at[mi], bv8[ni], accC[mi][ni], 0, 0, 0);
    }
    unsigned short* cdst = (unsigned short*)CTX;
#pragma unroll
    for (int mi = 0; mi < 2; ++mi)
#pragma unroll
        for (int ni = 0; ni < 8; ++ni)
#pragma unroll
            for (int r = 0; r < 4; ++r) {
                int q = wave * 32 + mi * 16 + g * 4 + r;
                int gm = b * 128 + q;
                int col = h * 128 + ni * 16 + rlo;
                cdst[(size_t)gm * 1024 + col] = bfbits(accC[mi][ni][r]);
            }
}

// ---------------- layernorm over rows of 1024 f32 ----------------
// MODE 0: also write bf16 (Hb)
template<int MODE>
__global__ __launch_bounds__(256)
void ln_k(const float* __restrict__ Y, const float* __restrict__ w, const float* __restrict__ b,
          float* __restrict__ Hf, bf16* __restrict__ Hb) {
    int row = blockIdx.x, tid = threadIdx.x;
    float4 v = reinterpret_cast<const float4*>(Y + (size_t)row * 1024)[tid];
    float s = v.x + v.y + v.z + v.w;
    float q = v.x * v.x + v.y * v.y + v.z * v.z + v.w * v.w;
#pragma unroll
    for (int o = 1; o < 64; o <<= 1) { s += __shfl_xor(s, o); q += __shfl_xor(q, o); }
    __shared__ float ss[4], sq[4];
    if ((tid & 63) == 0) { ss[tid >> 6] = s; sq[tid >> 6] = q; }
    __syncthreads();
    s = ss[0] + ss[1] + ss[2] + ss[3];
    q = sq[0] + sq[1] + sq[2] + sq[3];
    float u = s * (1.f / 1024.f);
    float var = fmaxf(q * (1.f / 1024.f) - u * u, 0.f);
    float rstd = rsqrtf(var + 1e-12f);
    float4 wv = reinterpret_cast<const float4*>(w)[tid];
    float4 bv = reinterpret_cast<const float4*>(b)[tid];
    float o0 = wv.x * (v.x - u) * rstd + bv.x;
    float o1 = wv.y * (v.y - u) * rstd + bv.y;
    float o2 = wv.z * (v.z - u) * rstd + bv.z;
    float o3 = wv.w * (v.w - u) * rstd + bv.w;
    reinterpret_cast<float4*>(Hf + (size_t)row * 1024)[tid] = make_float4(o0, o1, o2, o3);
    if constexpr (MODE == 0) {
        ushort4 ob;
        ob.x = bfbits(o0); ob.y = bfbits(o1); ob.z = bfbits(o2); ob.w = bfbits(o3);
        reinterpret_cast<ushort4*>(Hb)[row * 256 + tid] = ob;
    }
}

// ---- final LN: y = LN(PA + PB + b3 + resid), write f32 out ----
__global__ __launch_bounds__(256)
void ln2k(const float* __restrict__ PA, const float* __restrict__ PB,
          const float* __restrict__ b3, const float* __restrict__ resid,
          const float* __restrict__ w, const float* __restrict__ b,
          float* __restrict__ out) {
    int row = blockIdx.x, tid = threadIdx.x;
    size_t off = (size_t)row * 256 + tid;
    float4 pa = reinterpret_cast<const float4*>(PA)[off];
    float4 pb = reinterpret_cast<const float4*>(PB)[off];
    float4 bi = reinterpret_cast<const float4*>(b3)[tid];
    float4 rs = reinterpret_cast<const float4*>(resid)[off];
    float4 v = make_float4(pa.x + pb.x + bi.x + rs.x, pa.y + pb.y + bi.y + rs.y,
                           pa.z + pb.z + bi.z + rs.z, pa.w + pb.w + bi.w + rs.w);
    float s = v.x + v.y + v.z + v.w;
    float q = v.x * v.x + v.y * v.y + v.z * v.z + v.w * v.w;
#pragma unroll
    for (int o = 1; o < 64; o <<= 1) { s += __shfl_xor(s, o); q += __shfl_xor(q, o); }
    __shared__ float ss[4], sq[4];
    if ((tid & 63) == 0) { ss[tid >> 6] = s; sq[tid >> 6] = q; }
    __syncthreads();
    s = ss[0] + ss[1] + ss[2] + ss[3];
    q = sq[0] + sq[1] + sq[2] + sq[3];
    float u = s * (1.f / 1024.f);
    float var = fmaxf(q * (1.f / 1024.f) - u * u, 0.f);
    float rstd = rsqrtf(var + 1e-12f);
    float4 wv = reinterpret_cast<const float4*>(w)[tid];
    float4 bv = reinterpret_cast<const float4*>(b)[tid];
    float4 o4;
    o4.x = wv.x * (v.x - u) * rstd + bv.x;
    o4.y = wv.y * (v.y - u) * rstd + bv.y;
    o4.z = wv.z * (v.z - u) * rstd + bv.z;
    o4.w = wv.w * (v.w - u) * rstd + bv.w;
    reinterpret_cast<float4*>(out)[off] = o4;
}

extern "C" void kernel_launch(void* const* d_in, const int* in_sizes, int n_in,
                              void* d_out, int out_size, void* d_ws, size_t ws_size,
                              hipStream_t stream) {
    (void)in_sizes; (void)n_in; (void)out_size; (void)ws_size;
    const float* x    = (const float*)d_in[0];
    const float* Wq   = (const float*)d_in[2];
    const float* bq   = (const float*)d_in[3];
    const float* Wk   = (const float*)d_in[4];
    const float* bk   = (const float*)d_in[5];
    const float* Wv   = (const float*)d_in[6];
    const float* bv   = (const float*)d_in[7];
    const float* Wo   = (const float*)d_in[8];
    const float* bo   = (const float*)d_in[9];
    const float* ln1w = (const float*)d_in[10];
    const float* ln1b = (const float*)d_in[11];
    const float* W1   = (const float*)d_in[12];
    const float* b1   = (const float*)d_in[13];
    const float* W2   = (const float*)d_in[14];
    const float* b2   = (const float*)d_in[15];
    const float* W3   = (const float*)d_in[16];
    const float* b3   = (const float*)d_in[17];
    const float* ln2w = (const float*)d_in[18];
    const float* ln2b = (const float*)d_in[19];

    char* ws = (char*)d_ws;
    bf16*  XB    = (bf16*)(ws + 0);
    bf16*  WQKVB = (bf16*)(ws + 16777216);
    bf16*  WOB   = (bf16*)(ws + 23068672);
    bf16*  W1B   = (bf16*)(ws + 25165824);
    bf16*  W2B   = (bf16*)(ws + 29360128);
    bf16*  W3B   = (bf16*)(ws + 46137344);
    bf16*  Qb    = (bf16*)(ws + 54525952);
    bf16*  Kb    = (bf16*)(ws + 71303168);
    bf16*  Vb    = (bf16*)(ws + 88080384);
    bf16*  VTb   = (bf16*)(ws + 104857600);
    bf16*  Pb    = (bf16*)(ws + 121634816);
    bf16*  CTX   = (bf16*)(ws + 138412032);
    float* Y2    = (float*)(ws + 155189248);
    float* H32   = (float*)(ws + 188743680);
    bf16*  HB    = (bf16*)(ws + 222298112);
    bf16*  F1    = (bf16*)(ws + 155189248);   // overlays Y2 (dead after LN1)
    bf16*  F2    = (bf16*)(ws + 54525952);    // overlays Qb..VTb (dead)
    float* PW3   = (float*)(ws + 121634816);  // 67 MB span; clobbers Pb/CTX/Y2 (all dead by W3)

    auto cast = [&](const float* s, bf16* dd, int n4) {
        int nb = (n4 + 255) / 256; if (nb > 2048) nb = 2048;
        castk<<<nb, 256, 0, stream>>>(s, dd, n4);
    };
    cast(x,  XB,             2097152);
    cast(Wq, WQKVB,           262144);
    cast(Wk, WQKVB + 1048576, 262144);
    cast(Wv, WQKVB + 2097152, 262144);
    cast(Wo, WOB,             262144);
    cast(W1, W1B,             524288);
    cast(W2, W2B,            2097152);
    cast(W3, W3B,            1048576);

    // QKV: [8192,1024] @ [3072,1024]^T -> Q,K,V [B,H,S,DK]
    gemm256<0, 0><<<384, 512, 0, stream>>>(XB, WQKVB, 3072, 1024, 1024,
                                           bq, bk, bv, nullptr, Qb, Kb, Vb);
    transpose_v<<<512, 256, 0, stream>>>(Vb, VTb);
    attn_scores<<<512, 256, 0, stream>>>(Qb, Kb, Pb);
    attn_ctx<<<512, 256, 0, stream>>>(Pb, VTb, CTX);
    // attn_out + x -> Y2 (f32)
    gemm_bt<2><<<512, 256, 0, stream>>>(CTX, WOB, 8192, 1024, 1024, bo, x, (void*)Y2);
    ln_k<0><<<8192, 256, 0, stream>>>(Y2, ln1w, ln1b, H32, HB);
    // MLP
    gemm256<1, 0><<<256, 512, 0, stream>>>(HB, W1B, 2048, 1024, 1024,
                                           b1, nullptr, nullptr, (void*)F1, nullptr, nullptr, nullptr);
    gemm256<1, 0><<<512, 512, 0, stream>>>(F1, W2B, 4096, 2048, 2048,
                                           b2, nullptr, nullptr, (void*)F2, nullptr, nullptr, nullptr);
    // W3 split-K=2 -> f32 partials; reduce+bias+resid+LN fused in ln2k
    gemm256<2, 1><<<256, 512, 0, stream>>>(F2, W3B, 1024, 4096, 2048,
                                           nullptr, nullptr, nullptr, (void*)PW3, nullptr, nullptr, nullptr);
    ln2k<<<8192, 256, 0, stream>>>(PW3, PW3 + 8388608, b3, H32, ln2w, ln2b, (float*)d_out);
}